// Round 1
// 579.324 us; speedup vs baseline: 1.1750x; 1.1750x over previous
//
#include <hip/hip_runtime.h>

typedef _Float16 half_t;
typedef __attribute__((ext_vector_type(8))) _Float16 half8;
typedef __attribute__((ext_vector_type(4))) float floatx4;

#define BM 128
#define BN 128
#define BK 32

// ---------------- conversion + rearrange: W[d][s*C+c] -> Wt[c][s*D+d] fp16 ----------------
__global__ void cvt_w_kernel(const float* __restrict__ W, half_t* __restrict__ Wt,
                             int D, int C, int total) {
    int idx = blockIdx.x * blockDim.x + threadIdx.x;  // idx = c*1536 + s*512 + d
    if (idx >= total) return;
    int c = idx / 1536;
    int r = idx - c * 1536;           // s*512 + d
    int s = r >> 9;
    int d = r & 511;
    Wt[idx] = (half_t)W[(long)d * 1536 + s * 512 + c];
}

// ---------------- tanh(bias) table (for deg-0 rows) ----------------
__global__ void tanh_bias_kernel(const float* __restrict__ bias, float* __restrict__ tb, int C) {
    int c = blockIdx.x * blockDim.x + threadIdx.x;
    if (c >= C) return;
    float ex = __expf(2.0f * bias[c]);
    tb[c] = 1.0f - 2.0f / (ex + 1.0f);
}

// ---------------- counting sort of edges by dst ----------------
__global__ void hist_kernel(const int* __restrict__ dst, int* __restrict__ deg, int E) {
    int e = blockIdx.x * blockDim.x + threadIdx.x;
    if (e < E) atomicAdd(&deg[dst[e]], 1);
}

// partial sums of deg AND of flag(deg>0), per 1024-element block
__global__ void scan_partial2_kernel(const int* __restrict__ deg,
                                     int* __restrict__ bsum, int* __restrict__ bsum2, int n) {
    __shared__ int wsum[4], wsum2[4];
    int t = threadIdx.x, lane = t & 63, w = t >> 6;
    int base = blockIdx.x * 1024 + t * 4;
    int s = 0, s2 = 0;
#pragma unroll
    for (int j = 0; j < 4; ++j) {
        int i = base + j;
        if (i < n) { int d = deg[i]; s += d; s2 += (d > 0); }
    }
#pragma unroll
    for (int o = 1; o < 64; o <<= 1) { s += __shfl_xor(s, o); s2 += __shfl_xor(s2, o); }
    if (lane == 0) { wsum[w] = s; wsum2[w] = s2; }
    __syncthreads();
    if (t == 0) {
        bsum[blockIdx.x]  = wsum[0]  + wsum[1]  + wsum[2]  + wsum[3];
        bsum2[blockIdx.x] = wsum2[0] + wsum2[1] + wsum2[2] + wsum2[3];
    }
}

// single-wave exclusive scan of up to 128 elements in-place; returns total
__device__ int exscan_wave128(int* arr, int nb, int lane) {
    int a0 = (lane < nb) ? arr[lane] : 0;
    int a1 = (64 + lane < nb) ? arr[64 + lane] : 0;
    int s0 = a0, s1 = a1;
#pragma unroll
    for (int o = 1; o < 64; o <<= 1) {
        int t0 = __shfl_up(s0, o); if (lane >= o) s0 += t0;
        int t1 = __shfl_up(s1, o); if (lane >= o) s1 += t1;
    }
    s1 += __shfl(s0, 63);
    int tot = __shfl(s1, 63);
    if (lane < nb) arr[lane] = s0 - a0;
    if (64 + lane < nb) arr[64 + lane] = s1 - a1;
    return tot;
}

// wave-parallel scan of both block-sum arrays; writes Mc (= # nodes with deg>0)
__global__ void scan_bsums2_kernel(int* __restrict__ bsum, int* __restrict__ bsum2,
                                   int nb, int* __restrict__ mc) {
    int lane = threadIdx.x & 63;
    if (nb <= 128) {
        exscan_wave128(bsum, nb, lane);
        int tot = exscan_wave128(bsum2, nb, lane);
        if (lane == 0) *mc = tot;
    } else if (lane == 0) {
        int acc = 0, acc2 = 0;
        for (int i = 0; i < nb; ++i) {
            int v = bsum[i];  bsum[i] = acc;   acc += v;
            int v2 = bsum2[i]; bsum2[i] = acc2; acc2 += v2;
        }
        *mc = acc2;
    }
}

// final scan: edge offsets (off) + compact row rank + nodeid (compact->node)
__global__ void scan_final2_kernel(const int* __restrict__ deg,
                                   const int* __restrict__ bsum, const int* __restrict__ bsum2,
                                   int* __restrict__ off, int* __restrict__ rank,
                                   int* __restrict__ nodeid, int n) {
    __shared__ int wsum[4], wsum2[4];
    int t = threadIdx.x, lane = t & 63, w = t >> 6;
    int base = blockIdx.x * 1024 + t * 4;
    int v[4]; int s = 0, s2 = 0;
#pragma unroll
    for (int j = 0; j < 4; ++j) {
        int i = base + j;
        v[j] = (i < n) ? deg[i] : 0;
        s += v[j]; s2 += (v[j] > 0);
    }
    int sc = s, sc2 = s2;
#pragma unroll
    for (int o = 1; o < 64; o <<= 1) {
        int u  = __shfl_up(sc, o);  if (lane >= o) sc  += u;
        int u2 = __shfl_up(sc2, o); if (lane >= o) sc2 += u2;
    }
    if (lane == 63) { wsum[w] = sc; wsum2[w] = sc2; }
    __syncthreads();
    int woff = 0, woff2 = 0;
    for (int i = 0; i < w; ++i) { woff += wsum[i]; woff2 += wsum2[i]; }
    int ex  = bsum[blockIdx.x]  + woff  + (sc  - s);
    int ex2 = bsum2[blockIdx.x] + woff2 + (sc2 - s2);
#pragma unroll
    for (int j = 0; j < 4; ++j) {
        int i = base + j;
        if (i < n) {
            off[i] = ex;
            if (v[j] > 0) { rank[i] = ex2; nodeid[ex2] = i; ex2++; }
            ex += v[j];
        }
    }
}

__global__ void scatter_kernel(const int* __restrict__ dst, const int* __restrict__ off,
                               int* __restrict__ cursor, int* __restrict__ eidx, int E) {
    int e = blockIdx.x * blockDim.x + threadIdx.x;
    if (e >= E) return;
    int d = dst[e];
    int p = off[d] + atomicAdd(&cursor[d], 1);
    eidx[p] = e;
}

// ---------------- pre-aggregation: compacted Z[rank[n]][s*D+d] (deg>0 nodes only) ----------------
__global__ __launch_bounds__(256) void aggx_kernel(
    const float* __restrict__ x, const float* __restrict__ eta,
    const int* __restrict__ src, const int* __restrict__ off,
    const int* __restrict__ deg, const int* __restrict__ rank,
    const int* __restrict__ eidx, half_t* __restrict__ Z, int N, int D)
{
    int node = blockIdx.x * 4 + (threadIdx.x >> 6);
    if (node >= N) return;
    int d = deg[node];
    if (d == 0) return;  // deg-0 rows handled by fill_kernel; no Z row
    int lane = threadIdx.x & 63;

    float a0[8] = {}, a1[8] = {}, a2[8] = {};
    int start = off[node];
    for (int q = 0; q < d; ++q) {
        int e = eidx[start + q];
        int s = src[e];
        float e0 = eta[3 * e + 0], e1 = eta[3 * e + 1], e2 = eta[3 * e + 2];
        const float* xr = x + (long)s * D + lane * 8;
        floatx4 v0 = *(const floatx4*)xr;
        floatx4 v1 = *(const floatx4*)(xr + 4);
#pragma unroll
        for (int j = 0; j < 4; ++j) {
            a0[j] += e0 * v0[j]; a0[j + 4] += e0 * v1[j];
            a1[j] += e1 * v0[j]; a1[j + 4] += e1 * v1[j];
            a2[j] += e2 * v0[j]; a2[j + 4] += e2 * v1[j];
        }
    }
    half_t* zr = Z + (long)rank[node] * (3 * D) + lane * 8;
    half8 h0, h1, h2;
#pragma unroll
    for (int j = 0; j < 8; ++j) { h0[j] = (half_t)a0[j]; h1[j] = (half_t)a1[j]; h2[j] = (half_t)a2[j]; }
    *(half8*)zr = h0;
    *(half8*)(zr + D) = h1;
    *(half8*)(zr + 2 * D) = h2;
}

// ---------------- deg-0 rows: out[n] = tanh(bias) (precomputed row) ----------------
__global__ __launch_bounds__(256) void fill_kernel(const int* __restrict__ deg,
                                                   const float* __restrict__ tb,
                                                   float* __restrict__ out, int N, int C) {
    int node = blockIdx.x * 4 + (threadIdx.x >> 6);
    if (node >= N || deg[node] != 0) return;
    int lane = threadIdx.x & 63;
    float* o = out + (long)node * C;
    for (int c0 = lane * 8; c0 < C; c0 += 64 * 8) {
        floatx4 v0 = *(const floatx4*)(tb + c0);
        floatx4 v1 = *(const floatx4*)(tb + c0 + 4);
        *(floatx4*)(o + c0) = v0;
        *(floatx4*)(o + c0 + 4) = v1;
    }
}

// ---------------- GEMM + bias + tanh over compacted rows, epilogue scatter ----------------
// m97-style, k-octet XOR swizzle; XCD-bijective tile remap (m204) so the 4
// column-siblings of each A-panel run contiguously on one XCD's L2.
__global__ __launch_bounds__(256) void gemm_tanh_kernel(
    const half_t* __restrict__ A,    // compacted Z: [Mc][K], K=1536 (rows >= Mc: garbage, discarded)
    const half_t* __restrict__ Bt,   // Wt: [C][K]
    const float* __restrict__ bias,  // [C]
    const int* __restrict__ mc_ptr,  // &Mc
    const int* __restrict__ nodeid,  // compact row -> node
    float* __restrict__ out,         // [N][C]
    int K, int C)
{
    __shared__ half_t As[BM * BK];
    __shared__ half_t Bs[BN * BK];

    const int Mc = *mc_ptr;
    const int ncol = C / BN;                         // 4
    const int T = ((Mc + BM - 1) / BM) * ncol;       // live tiles
    const int b = blockIdx.x;
    if (b >= T) return;
    // bijective XCD swizzle: XCD(b)=b%8 (round-robin); give each XCD a contiguous
    // chunk of tile space, cols fastest -> A-panel fetched once per XCD L2.
    const int qq = T >> 3, rem = T & 7;
    const int xcd = b & 7, ib = b >> 3;
    const int wg = (xcd < rem ? xcd * (qq + 1) : rem * (qq + 1) + (xcd - rem) * qq) + ib;
    const int n0 = (wg % ncol) * BN;
    const int m0 = (wg / ncol) * BM;

    const int t    = threadIdx.x;
    const int lane = t & 63;
    const int wave = t >> 6;
    const int wm   = (wave >> 1) * 64;
    const int wn   = (wave & 1) * 64;

    // staging: thread t stages row r=t>>2 (and r+64), LDS slot t&3 (dest fixed: t*16B).
    // source octet swizzled: o_g = (t&3) ^ f(r), f(r)=(r>>1)&3 = (t>>3)&3 (same for r+64).
    const int r1 = t >> 2;
    const int r2 = r1 + 64;
    const int k8 = (((t & 3) ^ ((t >> 3) & 3))) * 8;
    const long gA1 = (long)(m0 + r1) * K + k8;   // Z padded to BM multiple: always in-bounds
    const long gA2 = (long)(m0 + r2) * K + k8;
    const long gB1 = (long)(n0 + r1) * K + k8;
    const long gB2 = (long)(n0 + r2) * K + k8;

    floatx4 acc[4][4] = {};

    const int mrow = wm + (lane & 15);
    const int nrow = wn + (lane & 15);
    const int koff = (((lane >> 4) ^ ((lane >> 1) & 3))) * 8;

    for (int kt = 0; kt < K; kt += BK) {
        __builtin_amdgcn_global_load_lds(
            (const __attribute__((address_space(1))) void*)(A + gA1 + kt),
            (__attribute__((address_space(3))) void*)(As + t * 8), 16, 0, 0);
        __builtin_amdgcn_global_load_lds(
            (const __attribute__((address_space(1))) void*)(A + gA2 + kt),
            (__attribute__((address_space(3))) void*)(As + (t + 256) * 8), 16, 0, 0);
        __builtin_amdgcn_global_load_lds(
            (const __attribute__((address_space(1))) void*)(Bt + gB1 + kt),
            (__attribute__((address_space(3))) void*)(Bs + t * 8), 16, 0, 0);
        __builtin_amdgcn_global_load_lds(
            (const __attribute__((address_space(1))) void*)(Bt + gB2 + kt),
            (__attribute__((address_space(3))) void*)(Bs + (t + 256) * 8), 16, 0, 0);
        __syncthreads();

        half8 af[4], bf[4];
#pragma unroll
        for (int i = 0; i < 4; ++i)
            af[i] = *(const half8*)&As[(mrow + i * 16) * BK + koff];
#pragma unroll
        for (int i = 0; i < 4; ++i)
            bf[i] = *(const half8*)&Bs[(nrow + i * 16) * BK + koff];
#pragma unroll
        for (int i = 0; i < 4; ++i)
#pragma unroll
            for (int j = 0; j < 4; ++j)
                acc[i][j] = __builtin_amdgcn_mfma_f32_16x16x32_f16(af[i], bf[j], acc[i][j], 0, 0, 0);
        __syncthreads();
    }

    // epilogue: D[m][n]: col = lane&15, row = (lane>>4)*4 + reg; scatter via nodeid; bias + tanh
    const int col0 = lane & 15;
    const int rbase = (lane >> 4) * 4;
    float bj[4];
#pragma unroll
    for (int j = 0; j < 4; ++j)
        bj[j] = bias[n0 + wn + col0 + j * 16];
#pragma unroll
    for (int i = 0; i < 4; ++i) {
#pragma unroll
        for (int rr = 0; rr < 4; ++rr) {
            int crow = m0 + wm + i * 16 + rbase + rr;
            if (crow >= Mc) continue;
            long base = (long)nodeid[crow] * C + n0 + wn + col0;
#pragma unroll
            for (int j = 0; j < 4; ++j) {
                float xv = acc[i][j][rr] + bj[j];
                float ex = __expf(2.0f * xv);
                out[base + j * 16] = 1.0f - 2.0f / (ex + 1.0f);
            }
        }
    }
}

extern "C" void kernel_launch(void* const* d_in, const int* in_sizes, int n_in,
                              void* d_out, int out_size, void* d_ws, size_t ws_size,
                              hipStream_t stream) {
    const float* x    = (const float*)d_in[0];
    const float* W    = (const float*)d_in[1];
    const float* bias = (const float*)d_in[2];
    const float* eta  = (const float*)d_in[3];
    const int*   src  = (const int*)d_in[4];
    const int*   dst  = (const int*)d_in[5];
    float* out = (float*)d_out;

    const int  C   = in_sizes[2];          // 512
    const int  C3  = 3 * C;                // 1536
    const int  D   = in_sizes[1] / C3;     // 512
    const long xcount = in_sizes[0];       // N*D
    const int  N   = (int)(xcount / D);    // 100000
    const int  E   = in_sizes[4];          // 100000
    const int  K   = 3 * D;                // 1536 (GEMM inner dim)
    const int  Npad = ((N + BM - 1) / BM) * BM;   // Z padded so GEMM A-tiles never go OOB
    const int  nb  = (N + 1023) / 1024;
    const size_t nbPad = (size_t)((nb + 3) & ~3); // 16B-aligned chunks

    // workspace layout (16B-aligned): Z | Wt | deg | cursor | off | rank | nodeid | eidx | bsum | bsum2 | mc | tb
    char* ws = (char*)d_ws;
    size_t o = 0;
    half_t* Z    = (half_t*)(ws + o); o += (size_t)Npad * K * sizeof(half_t);
    half_t* Wt_h = (half_t*)(ws + o); o += (size_t)C * K * sizeof(half_t);
    int* deg     = (int*)(ws + o);    o += (size_t)N * sizeof(int);
    int* cursor  = (int*)(ws + o);    o += (size_t)N * sizeof(int);
    int* off     = (int*)(ws + o);    o += (size_t)N * sizeof(int);
    int* rank    = (int*)(ws + o);    o += (size_t)N * sizeof(int);
    int* nodeid  = (int*)(ws + o);    o += (size_t)N * sizeof(int);
    int* eidx    = (int*)(ws + o);    o += (size_t)E * sizeof(int);
    int* bsum    = (int*)(ws + o);    o += nbPad * sizeof(int);
    int* bsum2   = (int*)(ws + o);    o += nbPad * sizeof(int);
    int* mc      = (int*)(ws + o);    o += 4 * sizeof(int);
    float* tb    = (float*)(ws + o);  o += (size_t)C * sizeof(float);

    // 0. zero deg + cursor (adjacent)
    hipMemsetAsync(deg, 0, 2 * (size_t)N * sizeof(int), stream);
    // 1. W -> fp16 [C][3*D]; tanh(bias) table
    cvt_w_kernel<<<(C * K + 255) / 256, 256, 0, stream>>>(W, Wt_h, D, C, C * K);
    tanh_bias_kernel<<<(C + 255) / 256, 256, 0, stream>>>(bias, tb, C);
    // 2. counting sort of edges by dst + compaction scan (rank/nodeid/Mc)
    hist_kernel<<<(E + 255) / 256, 256, 0, stream>>>(dst, deg, E);
    scan_partial2_kernel<<<nb, 256, 0, stream>>>(deg, bsum, bsum2, N);
    scan_bsums2_kernel<<<1, 64, 0, stream>>>(bsum, bsum2, nb, mc);
    scan_final2_kernel<<<nb, 256, 0, stream>>>(deg, bsum, bsum2, off, rank, nodeid, N);
    scatter_kernel<<<(E + 255) / 256, 256, 0, stream>>>(dst, off, cursor, eidx, E);
    // 3. pre-aggregation on x -> compacted Z (fp16); deg-0 rows -> tanh(bias)
    aggx_kernel<<<(N + 3) / 4, 256, 0, stream>>>(x, eta, src, off, deg, rank, eidx, Z, N, D);
    fill_kernel<<<(N + 3) / 4, 256, 0, stream>>>(deg, tb, out, N, C);
    // 4. fused GEMM + bias + tanh over Mc compacted rows (early-exit beyond live tiles)
    {
        const int nwg = ((N + BM - 1) / BM) * (C / BN);
        gemm_tanh_kernel<<<nwg, 256, 0, stream>>>(Z, Wt_h, bias, mc, nodeid, out, K, C);
    }
}

// Round 2
// 546.040 us; speedup vs baseline: 1.2467x; 1.0610x over previous
//
#include <hip/hip_runtime.h>

typedef _Float16 half_t;
typedef __attribute__((ext_vector_type(8))) _Float16 half8;
typedef __attribute__((ext_vector_type(4))) float floatx4;

#define BM 128
#define BN 128
#define BK 32

// ---------------- conversion + rearrange: W[d][s*C+c] -> Wt[c][s*D+d] fp16 ----------------
// also computes tanh(bias) table (threads idx < C)
__global__ void cvt_w_kernel(const float* __restrict__ W, half_t* __restrict__ Wt,
                             const float* __restrict__ bias, float* __restrict__ tb,
                             int D, int C, int total) {
    int idx = blockIdx.x * blockDim.x + threadIdx.x;  // idx = c*1536 + s*512 + d
    if (idx >= total) return;
    if (idx < C) {
        float ex = __expf(2.0f * bias[idx]);
        tb[idx] = 1.0f - 2.0f / (ex + 1.0f);
    }
    int c = idx / 1536;
    int r = idx - c * 1536;           // s*512 + d
    int s = r >> 9;
    int d = r & 511;
    Wt[idx] = (half_t)W[(long)d * 1536 + s * 512 + c];
}

// ---------------- counting sort of edges by dst ----------------
__global__ void hist_kernel(const int* __restrict__ dst, int* __restrict__ deg, int E) {
    int e = blockIdx.x * blockDim.x + threadIdx.x;
    if (e < E) atomicAdd(&deg[dst[e]], 1);
}

// partial sums of deg AND of flag(deg>0), per 1024-element block
__global__ void scan_partial2_kernel(const int* __restrict__ deg,
                                     int* __restrict__ bsum, int* __restrict__ bsum2, int n) {
    __shared__ int wsum[4], wsum2[4];
    int t = threadIdx.x, lane = t & 63, w = t >> 6;
    int base = blockIdx.x * 1024 + t * 4;
    int s = 0, s2 = 0;
#pragma unroll
    for (int j = 0; j < 4; ++j) {
        int i = base + j;
        if (i < n) { int d = deg[i]; s += d; s2 += (d > 0); }
    }
#pragma unroll
    for (int o = 1; o < 64; o <<= 1) { s += __shfl_xor(s, o); s2 += __shfl_xor(s2, o); }
    if (lane == 0) { wsum[w] = s; wsum2[w] = s2; }
    __syncthreads();
    if (t == 0) {
        bsum[blockIdx.x]  = wsum[0]  + wsum[1]  + wsum[2]  + wsum[3];
        bsum2[blockIdx.x] = wsum2[0] + wsum2[1] + wsum2[2] + wsum2[3];
    }
}

// single-wave exclusive scan of up to 128 elements in-place; returns total
__device__ int exscan_wave128(int* arr, int nb, int lane) {
    int a0 = (lane < nb) ? arr[lane] : 0;
    int a1 = (64 + lane < nb) ? arr[64 + lane] : 0;
    int s0 = a0, s1 = a1;
#pragma unroll
    for (int o = 1; o < 64; o <<= 1) {
        int t0 = __shfl_up(s0, o); if (lane >= o) s0 += t0;
        int t1 = __shfl_up(s1, o); if (lane >= o) s1 += t1;
    }
    s1 += __shfl(s0, 63);
    int tot = __shfl(s1, 63);
    if (lane < nb) arr[lane] = s0 - a0;
    if (64 + lane < nb) arr[64 + lane] = s1 - a1;
    return tot;
}

__global__ void scan_bsums2_kernel(int* __restrict__ bsum, int* __restrict__ bsum2,
                                   int nb, int* __restrict__ mc) {
    int lane = threadIdx.x & 63;
    if (nb <= 128) {
        exscan_wave128(bsum, nb, lane);
        int tot = exscan_wave128(bsum2, nb, lane);
        if (lane == 0) *mc = tot;
    } else if (lane == 0) {
        int acc = 0, acc2 = 0;
        for (int i = 0; i < nb; ++i) {
            int v = bsum[i];  bsum[i] = acc;   acc += v;
            int v2 = bsum2[i]; bsum2[i] = acc2; acc2 += v2;
        }
        *mc = acc2;
    }
}

// final scan: edge offsets (off) + compact row rank + nodeid (compact->node)
__global__ void scan_final2_kernel(const int* __restrict__ deg,
                                   const int* __restrict__ bsum, const int* __restrict__ bsum2,
                                   int* __restrict__ off, int* __restrict__ rank,
                                   int* __restrict__ nodeid, int n) {
    __shared__ int wsum[4], wsum2[4];
    int t = threadIdx.x, lane = t & 63, w = t >> 6;
    int base = blockIdx.x * 1024 + t * 4;
    int v[4]; int s = 0, s2 = 0;
#pragma unroll
    for (int j = 0; j < 4; ++j) {
        int i = base + j;
        v[j] = (i < n) ? deg[i] : 0;
        s += v[j]; s2 += (v[j] > 0);
    }
    int sc = s, sc2 = s2;
#pragma unroll
    for (int o = 1; o < 64; o <<= 1) {
        int u  = __shfl_up(sc, o);  if (lane >= o) sc  += u;
        int u2 = __shfl_up(sc2, o); if (lane >= o) sc2 += u2;
    }
    if (lane == 63) { wsum[w] = sc; wsum2[w] = sc2; }
    __syncthreads();
    int woff = 0, woff2 = 0;
    for (int i = 0; i < w; ++i) { woff += wsum[i]; woff2 += wsum2[i]; }
    int ex  = bsum[blockIdx.x]  + woff  + (sc  - s);
    int ex2 = bsum2[blockIdx.x] + woff2 + (sc2 - s2);
#pragma unroll
    for (int j = 0; j < 4; ++j) {
        int i = base + j;
        if (i < n) {
            off[i] = ex;
            if (v[j] > 0) { rank[i] = ex2; nodeid[ex2] = i; ex2++; }
            ex += v[j];
        }
    }
}

// scatter: edges sorted by dst; also pre-gathers src + eta so aggx has a 2-level chain
__global__ void scatter_kernel(const int* __restrict__ dst, const int* __restrict__ src,
                               const float* __restrict__ eta,
                               const int* __restrict__ off, int* __restrict__ cursor,
                               int* __restrict__ srcs, floatx4* __restrict__ etas, int E) {
    int e = blockIdx.x * blockDim.x + threadIdx.x;
    if (e >= E) return;
    int d = dst[e];
    int p = off[d] + atomicAdd(&cursor[d], 1);
    srcs[p] = src[e];
    floatx4 et;
    et[0] = eta[3 * e + 0]; et[1] = eta[3 * e + 1]; et[2] = eta[3 * e + 2]; et[3] = 0.0f;
    etas[p] = et;
}

// ---------------- pre-aggregation: compacted Z[rank[n]][s*D+d]; deg-0 -> out=tanh(bias) ----------------
__global__ __launch_bounds__(256) void aggx_kernel(
    const float* __restrict__ x, const int* __restrict__ srcs,
    const floatx4* __restrict__ etas, const int* __restrict__ off,
    const int* __restrict__ deg, const int* __restrict__ rank,
    const float* __restrict__ tb, float* __restrict__ out,
    half_t* __restrict__ Z, int N, int D, int C)
{
    int node = blockIdx.x * 4 + (threadIdx.x >> 6);
    if (node >= N) return;
    int lane = threadIdx.x & 63;
    int d = deg[node];
    if (d == 0) {
        // no in-edges: out row = tanh(bias) (precomputed); no Z row
        float* o = out + (long)node * C;
        for (int c0 = lane * 8; c0 < C; c0 += 64 * 8) {
            floatx4 v0 = *(const floatx4*)(tb + c0);
            floatx4 v1 = *(const floatx4*)(tb + c0 + 4);
            *(floatx4*)(o + c0) = v0;
            *(floatx4*)(o + c0 + 4) = v1;
        }
        return;
    }

    float a0[8] = {}, a1[8] = {}, a2[8] = {};
    int start = off[node];
    for (int q = 0; q < d; ++q) {
        int s = srcs[start + q];          // wave-uniform broadcast
        floatx4 et = etas[start + q];     // wave-uniform broadcast
        const float* xr = x + (long)s * D + lane * 8;
        floatx4 v0 = *(const floatx4*)xr;
        floatx4 v1 = *(const floatx4*)(xr + 4);
#pragma unroll
        for (int j = 0; j < 4; ++j) {
            a0[j] += et[0] * v0[j]; a0[j + 4] += et[0] * v1[j];
            a1[j] += et[1] * v0[j]; a1[j + 4] += et[1] * v1[j];
            a2[j] += et[2] * v0[j]; a2[j + 4] += et[2] * v1[j];
        }
    }
    half_t* zr = Z + (long)rank[node] * (3 * D) + lane * 8;
    half8 h0, h1, h2;
#pragma unroll
    for (int j = 0; j < 8; ++j) { h0[j] = (half_t)a0[j]; h1[j] = (half_t)a1[j]; h2[j] = (half_t)a2[j]; }
    *(half8*)zr = h0;
    *(half8*)(zr + D) = h1;
    *(half8*)(zr + 2 * D) = h2;
}

// ---------------- GEMM + bias + tanh over compacted rows, epilogue scatter ----------------
// 128^2 tile, double-buffered LDS, counted vmcnt(4) + raw s_barrier (m139 pattern):
// STAGE(t+1) issued a full K-step ahead; loads stay in flight across the barrier.
__global__ __launch_bounds__(256) void gemm_tanh_kernel(
    const half_t* __restrict__ A,    // compacted Z: [Mc][K], K=1536
    const half_t* __restrict__ Bt,   // Wt: [C][K]
    const float* __restrict__ bias,  // [C]
    const int* __restrict__ mc_ptr,  // &Mc
    const int* __restrict__ nodeid,  // compact row -> node
    float* __restrict__ out,         // [N][C]
    int K, int C)
{
    __shared__ half_t As[2][BM * BK];
    __shared__ half_t Bs[2][BN * BK];

    const int Mc = *mc_ptr;
    const int ncol = C / BN;                         // 4
    const int T = ((Mc + BM - 1) / BM) * ncol;       // live tiles
    const int b = blockIdx.x;
    if (b >= T) return;
    // bijective XCD swizzle (m204): contiguous tile chunk per XCD, cols fastest
    const int qq = T >> 3, rem = T & 7;
    const int xcd = b & 7, ib = b >> 3;
    const int wg = (xcd < rem ? xcd * (qq + 1) : rem * (qq + 1) + (xcd - rem) * qq) + ib;
    const int n0 = (wg % ncol) * BN;
    const int m0 = (wg / ncol) * BM;

    const int t    = threadIdx.x;
    const int lane = t & 63;
    const int wave = t >> 6;
    const int wm   = (wave >> 1) * 64;
    const int wn   = (wave & 1) * 64;

    // staging: thread t stages row r=t>>2 (and r+64), LDS slot t&3 (dest linear: t*16B).
    // source octet swizzled: o_g = (t&3) ^ ((t>>3)&3)  (both-sides-or-neither, rule #21)
    const int r1 = t >> 2;
    const int r2 = r1 + 64;
    const int k8 = (((t & 3) ^ ((t >> 3) & 3))) * 8;
    const long gA1 = (long)(m0 + r1) * K + k8;   // Z padded to BM multiple: in-bounds
    const long gA2 = (long)(m0 + r2) * K + k8;
    const long gB1 = (long)(n0 + r1) * K + k8;
    const long gB2 = (long)(n0 + r2) * K + k8;

    floatx4 acc[4][4] = {};

    const int mrow = wm + (lane & 15);
    const int nrow = wn + (lane & 15);
    const int koff = (((lane >> 4) ^ ((lane >> 1) & 3))) * 8;

#define STAGE(buf, kt)                                                                     \
    do {                                                                                   \
        __builtin_amdgcn_global_load_lds(                                                  \
            (const __attribute__((address_space(1))) void*)(A + gA1 + (kt)),               \
            (__attribute__((address_space(3))) void*)(&As[buf][t * 8]), 16, 0, 0);         \
        __builtin_amdgcn_global_load_lds(                                                  \
            (const __attribute__((address_space(1))) void*)(A + gA2 + (kt)),               \
            (__attribute__((address_space(3))) void*)(&As[buf][(t + 256) * 8]), 16, 0, 0); \
        __builtin_amdgcn_global_load_lds(                                                  \
            (const __attribute__((address_space(1))) void*)(Bt + gB1 + (kt)),              \
            (__attribute__((address_space(3))) void*)(&Bs[buf][t * 8]), 16, 0, 0);         \
        __builtin_amdgcn_global_load_lds(                                                  \
            (const __attribute__((address_space(1))) void*)(Bt + gB2 + (kt)),              \
            (__attribute__((address_space(3))) void*)(&Bs[buf][(t + 256) * 8]), 16, 0, 0); \
    } while (0)

#define COMPUTE(buf)                                                                       \
    do {                                                                                   \
        half8 af[4], bf[4];                                                                \
        _Pragma("unroll") for (int i = 0; i < 4; ++i)                                      \
            af[i] = *(const half8*)&As[buf][(mrow + i * 16) * BK + koff];                   \
        _Pragma("unroll") for (int i = 0; i < 4; ++i)                                      \
            bf[i] = *(const half8*)&Bs[buf][(nrow + i * 16) * BK + koff];                   \
        _Pragma("unroll") for (int i = 0; i < 4; ++i)                                      \
            _Pragma("unroll") for (int j = 0; j < 4; ++j)                                  \
                acc[i][j] = __builtin_amdgcn_mfma_f32_16x16x32_f16(af[i], bf[j],           \
                                                                   acc[i][j], 0, 0, 0);   \
    } while (0)

    const int nsteps = K / BK;   // 48
    STAGE(0, 0);
    int cur = 0;
    for (int ks = 1; ks < nsteps; ++ks) {
        STAGE(cur ^ 1, ks * BK);                       // prefetch next tile (in flight)
        asm volatile("s_waitcnt vmcnt(4)" ::: "memory"); // wait ONLY current tile's 4 loads
        __builtin_amdgcn_sched_barrier(0);
        __builtin_amdgcn_s_barrier();                  // all waves: buf[cur] complete
        __builtin_amdgcn_sched_barrier(0);
        COMPUTE(cur);
        __builtin_amdgcn_sched_barrier(0);
        __builtin_amdgcn_s_barrier();                  // all waves done reading buf[cur]
        __builtin_amdgcn_sched_barrier(0);
        cur ^= 1;
    }
    asm volatile("s_waitcnt vmcnt(0)" ::: "memory");
    __builtin_amdgcn_sched_barrier(0);
    __builtin_amdgcn_s_barrier();
    __builtin_amdgcn_sched_barrier(0);
    COMPUTE(cur);

#undef STAGE
#undef COMPUTE

    // epilogue: D[m][n]: col = lane&15, row = (lane>>4)*4 + reg; scatter via nodeid; bias + tanh
    const int col0 = lane & 15;
    const int rbase = (lane >> 4) * 4;
    float bj[4];
#pragma unroll
    for (int j = 0; j < 4; ++j)
        bj[j] = bias[n0 + wn + col0 + j * 16];
#pragma unroll
    for (int i = 0; i < 4; ++i) {
#pragma unroll
        for (int rr = 0; rr < 4; ++rr) {
            int crow = m0 + wm + i * 16 + rbase + rr;
            if (crow >= Mc) continue;
            long base = (long)nodeid[crow] * C + n0 + wn + col0;
#pragma unroll
            for (int j = 0; j < 4; ++j) {
                float xv = acc[i][j][rr] + bj[j];
                float ex = __expf(2.0f * xv);
                out[base + j * 16] = 1.0f - 2.0f / (ex + 1.0f);
            }
        }
    }
}

extern "C" void kernel_launch(void* const* d_in, const int* in_sizes, int n_in,
                              void* d_out, int out_size, void* d_ws, size_t ws_size,
                              hipStream_t stream) {
    const float* x    = (const float*)d_in[0];
    const float* W    = (const float*)d_in[1];
    const float* bias = (const float*)d_in[2];
    const float* eta  = (const float*)d_in[3];
    const int*   src  = (const int*)d_in[4];
    const int*   dst  = (const int*)d_in[5];
    float* out = (float*)d_out;

    const int  C   = in_sizes[2];          // 512
    const int  C3  = 3 * C;                // 1536
    const int  D   = in_sizes[1] / C3;     // 512
    const long xcount = in_sizes[0];       // N*D
    const int  N   = (int)(xcount / D);    // 100000
    const int  E   = in_sizes[4];          // 100000
    const int  K   = 3 * D;                // 1536 (GEMM inner dim)
    const int  Npad = ((N + BM - 1) / BM) * BM;
    const int  nb  = (N + 1023) / 1024;
    const size_t nbPad = (size_t)((nb + 3) & ~3);

    auto alignup = [](size_t v) { return (v + 15) & ~(size_t)15; };

    // workspace: Z | Wt | deg | cursor | off | rank | nodeid | srcs | etas | bsum | bsum2 | mc | tb
    char* ws = (char*)d_ws;
    size_t o = 0;
    half_t* Z    = (half_t*)(ws + o); o += (size_t)Npad * K * sizeof(half_t);
    half_t* Wt_h = (half_t*)(ws + o); o += (size_t)C * K * sizeof(half_t);
    int* deg     = (int*)(ws + o);    o += (size_t)N * sizeof(int);
    int* cursor  = (int*)(ws + o);    o += (size_t)N * sizeof(int);
    int* off     = (int*)(ws + o);    o += (size_t)N * sizeof(int);
    int* rank    = (int*)(ws + o);    o += (size_t)N * sizeof(int);
    int* nodeid  = (int*)(ws + o);    o += (size_t)N * sizeof(int);
    int* srcs    = (int*)(ws + o);    o += (size_t)E * sizeof(int);
    o = alignup(o);
    floatx4* etas = (floatx4*)(ws + o); o += (size_t)E * sizeof(floatx4);
    int* bsum    = (int*)(ws + o);    o += nbPad * sizeof(int);
    int* bsum2   = (int*)(ws + o);    o += nbPad * sizeof(int);
    int* mc      = (int*)(ws + o);    o += 4 * sizeof(int);
    float* tb    = (float*)(ws + o);  o += (size_t)C * sizeof(float);

    // 0. zero deg + cursor (adjacent)
    hipMemsetAsync(deg, 0, 2 * (size_t)N * sizeof(int), stream);
    // 1. W -> fp16 [C][3*D] + tanh(bias) table
    cvt_w_kernel<<<(C * K + 255) / 256, 256, 0, stream>>>(W, Wt_h, bias, tb, D, C, C * K);
    // 2. counting sort of edges by dst + compaction scan (rank/nodeid/Mc)
    hist_kernel<<<(E + 255) / 256, 256, 0, stream>>>(dst, deg, E);
    scan_partial2_kernel<<<nb, 256, 0, stream>>>(deg, bsum, bsum2, N);
    scan_bsums2_kernel<<<1, 64, 0, stream>>>(bsum, bsum2, nb, mc);
    scan_final2_kernel<<<nb, 256, 0, stream>>>(deg, bsum, bsum2, off, rank, nodeid, N);
    scatter_kernel<<<(E + 255) / 256, 256, 0, stream>>>(dst, src, eta, off, cursor, srcs, etas, E);
    // 3. pre-aggregation -> compacted Z (fp16); deg-0 rows -> tanh(bias) row
    aggx_kernel<<<(N + 3) / 4, 256, 0, stream>>>(x, srcs, etas, off, deg, rank, tb, out, Z, N, D, C);
    // 4. fused GEMM + bias + tanh over Mc compacted rows (early-exit beyond live tiles)
    {
        const int nwg = ((N + BM - 1) / BM) * (C / BN);
        gemm_tanh_kernel<<<nwg, 256, 0, stream>>>(Z, Wt_h, bias, mc, nodeid, out, K, C);
    }
}